// Round 3
// baseline (204.324 us; speedup 1.0000x reference)
//
#include <hip/hip_runtime.h>
#include <math.h>

// GradientBoostingLoss: per-row top-4 hardest negatives + logsumexp, mean over rows.
// R3: software-pipelined 4 rows/wave (next row's loads issued before current row's
// sort/merge/butterfly), sort4+bitonic-merge per-lane top-4 (76 VALU vs 176),
// single-shfl label broadcast, 2048 partials + tiny reducer. No same-address atomics.

#define WPB 4   // waves per block (256 threads)
#define RPW 4   // rows per wave (pipeline depth)

__device__ __forceinline__ void ce(float &a, float &b) {
    float hi = fmaxf(a, b), lo = fminf(a, b); a = hi; b = lo;
}

// Sort float4 descending (x >= y >= z >= w): 5 compare-exchanges.
__device__ __forceinline__ void sort4d(float4 &v) {
    ce(v.x, v.y); ce(v.z, v.w); ce(v.x, v.z); ce(v.y, v.w); ce(v.y, v.z);
}

// Merge two sorted-desc top-4 lists -> sorted-desc top-4 of the union (12 ops).
__device__ __forceinline__ void merge4(float o0, float o1, float o2, float o3,
                                       float &t0, float &t1, float &t2, float &t3) {
    float c0 = fmaxf(t0, o3);
    float c1 = fmaxf(t1, o2);
    float c2 = fmaxf(t2, o1);
    float c3 = fmaxf(t3, o0);             // bitonic top-4 multiset
    float d0 = fmaxf(c0, c2), d2 = fminf(c0, c2);
    float d1 = fmaxf(c1, c3), d3 = fminf(c1, c3);
    t0 = fmaxf(d0, d1); t1 = fminf(d0, d1);
    t2 = fmaxf(d2, d3); t3 = fminf(d2, d3);
}

// Capture the true-label logit from quad q (if it lives there) and mask it to -inf.
__device__ __forceinline__ void grab(float4 &v, int q, int qL, int sub, float &labv) {
    if (q == qL) {
        labv = (sub == 0) ? v.x : (sub == 1) ? v.y : (sub == 2) ? v.z : v.w;
        if      (sub == 0) v.x = -INFINITY;
        else if (sub == 1) v.y = -INFINITY;
        else if (sub == 2) v.z = -INFINITY;
        else               v.w = -INFINITY;
    }
}

// Pipelined kernel, compile-time quads-per-row NQ in (192, 256].
template<int NQ>
__global__ __launch_bounds__(256) void topk_pipe(
    const float* __restrict__ logits, const int* __restrict__ labels,
    float* __restrict__ partial, int B)
{
    static_assert(NQ > 192 && NQ <= 256, "pipelined path requires 192 < NQ <= 256");
    const int wid   = threadIdx.x >> 6;
    const int lane  = threadIdx.x & 63;
    const int rbase = (blockIdx.x * WPB + wid) * RPW;

    const int  q0 = lane, q1 = lane + 64, q2 = lane + 128;
    const bool v3 = (lane + 192) < NQ;
    const int  q3 = v3 ? (lane + 192) : (NQ - 1);   // clamped duplicate read

    float4 c0, c1, c2, c3;
    int Lc;
    {
        const int row = rbase < B ? rbase : B - 1;
        const float4* rp = (const float4*)(logits + (size_t)row * (size_t)(NQ * 4));
        c0 = rp[q0]; c1 = rp[q1]; c2 = rp[q2]; c3 = rp[q3];
        Lc = labels[row];
    }

    float lsum = 0.0f;

    #pragma unroll
    for (int r = 0; r < RPW; ++r) {
        const int row = rbase + r;

        // ---- issue next row's loads first (they cover this row's compute) ----
        float4 n0, n1, n2, n3; int Ln = 0;
        if (r + 1 < RPW) {
            const int nrow = (row + 1) < B ? (row + 1) : B - 1;
            const float4* rp = (const float4*)(logits + (size_t)nrow * (size_t)(NQ * 4));
            n0 = rp[q0]; n1 = rp[q1]; n2 = rp[q2]; n3 = rp[q3];
            Ln = labels[nrow];
        }

        // ---- process current row ----
        const int qL = Lc >> 2, sub = Lc & 3;
        float labv = -INFINITY;
        grab(c0, q0, qL, sub, labv);
        grab(c1, q1, qL, sub, labv);
        grab(c2, q2, qL, sub, labv);
        grab(c3, q3, qL, sub, labv);      // clamped lanes may spuriously capture; harmless
        // Owner lane of the label quad is qL & 63 (qL < NQ), always a valid-v3 lane
        // when qL >= 192. One shuffle replaces a 6-stage max-reduce.
        const float lab = __shfl(labv, qL & 63, 64);
        if (!v3) c3 = make_float4(-INFINITY, -INFINITY, -INFINITY, -INFINITY);

        // Per-lane top-4 of 16 values: 4x sort4 (40) + 3x merge4 (36).
        sort4d(c0); sort4d(c1); sort4d(c2); sort4d(c3);
        merge4(c1.x, c1.y, c1.z, c1.w, c0.x, c0.y, c0.z, c0.w);
        merge4(c3.x, c3.y, c3.z, c3.w, c2.x, c2.y, c2.z, c2.w);
        merge4(c2.x, c2.y, c2.z, c2.w, c0.x, c0.y, c0.z, c0.w);
        float t0 = c0.x, t1 = c0.y, t2 = c0.z, t3 = c0.w;

        // Butterfly all-reduce: disjoint XOR groups per stage -> valid for top-k.
        #pragma unroll
        for (int m = 1; m < 64; m <<= 1) {
            float o0 = __shfl_xor(t0, m, 64);
            float o1 = __shfl_xor(t1, m, 64);
            float o2 = __shfl_xor(t2, m, 64);
            float o3 = __shfl_xor(t3, m, 64);
            merge4(o0, o1, o2, o3, t0, t1, t2, t3);
        }

        // loss = logsumexp([lab, t0..t3]) - lab
        float mx = fmaxf(lab, t0);
        float s  = expf(lab - mx) + expf(t0 - mx) + expf(t1 - mx)
                 + expf(t2 - mx) + expf(t3 - mx);
        if (row < B) lsum += logf(s) + mx - lab;   // uniform predicate

        c0 = n0; c1 = n1; c2 = n2; c3 = n3; Lc = Ln;
    }

    __shared__ float s_loss[WPB];
    if (lane == 0) s_loss[wid] = lsum;
    __syncthreads();
    if (threadIdx.x == 0)
        partial[blockIdx.x] = s_loss[0] + s_loss[1] + s_loss[2] + s_loss[3];
}

// Generic fallback (1 row per wave, grid-stride over quads) for shapes != C=1000.
__global__ __launch_bounds__(256) void topk_generic(
    const float* __restrict__ logits, const int* __restrict__ labels,
    float* __restrict__ partial, int B, int C)
{
    const int wid  = threadIdx.x >> 6;
    const int lane = threadIdx.x & 63;
    const int row  = blockIdx.x * WPB + wid;

    __shared__ float s_loss[WPB];
    float loss = 0.0f;
    if (row < B) {
        const float4* rp = (const float4*)(logits + (size_t)row * (size_t)C);
        const int nq  = C >> 2;
        const int L   = labels[row];
        const int qL  = L >> 2;
        const int sub = L & 3;

        float t0 = -INFINITY, t1 = -INFINITY, t2 = -INFINITY, t3 = -INFINITY;
        float labv = -INFINITY;
        for (int q = lane; q < nq; q += 64) {
            float4 v = rp[q];
            grab(v, q, qL, sub, labv);
            sort4d(v);
            merge4(v.x, v.y, v.z, v.w, t0, t1, t2, t3);
        }
        // scalar remainder elements (C % 4)
        for (int c = (nq << 2) + lane; c < C; c += 64) {
            float v = logits[(size_t)row * (size_t)C + c];
            if (c == L) { labv = v; v = -INFINITY; }
            merge4(v, -INFINITY, -INFINITY, -INFINITY, t0, t1, t2, t3);
        }
        float lab = labv;
        #pragma unroll
        for (int m = 1; m < 64; m <<= 1) {
            float o0 = __shfl_xor(t0, m, 64);
            float o1 = __shfl_xor(t1, m, 64);
            float o2 = __shfl_xor(t2, m, 64);
            float o3 = __shfl_xor(t3, m, 64);
            float ol = __shfl_xor(lab, m, 64);
            merge4(o0, o1, o2, o3, t0, t1, t2, t3);
            lab = fmaxf(lab, ol);
        }
        float mx = fmaxf(lab, t0);
        float s  = expf(lab - mx) + expf(t0 - mx) + expf(t1 - mx)
                 + expf(t2 - mx) + expf(t3 - mx);
        loss = logf(s) + mx - lab;
    }

    if (lane == 0) s_loss[wid] = loss;
    __syncthreads();
    if (threadIdx.x == 0)
        partial[blockIdx.x] = s_loss[0] + s_loss[1] + s_loss[2] + s_loss[3];
}

__global__ __launch_bounds__(256) void reduce_partials(
    const float* __restrict__ partial, float* __restrict__ out, int n, float invB)
{
    __shared__ float s_sum[WPB];
    float s = 0.0f;
    for (int i = threadIdx.x; i < n; i += 256) s += partial[i];
    #pragma unroll
    for (int m = 32; m >= 1; m >>= 1) s += __shfl_down(s, m, 64);
    const int wid  = threadIdx.x >> 6;
    const int lane = threadIdx.x & 63;
    if (lane == 0) s_sum[wid] = s;
    __syncthreads();
    if (threadIdx.x == 0)
        *out = (s_sum[0] + s_sum[1] + s_sum[2] + s_sum[3]) * invB;
}

extern "C" void kernel_launch(void* const* d_in, const int* in_sizes, int n_in,
                              void* d_out, int out_size, void* d_ws, size_t ws_size,
                              hipStream_t stream) {
    const float* logits = (const float*)d_in[0];
    const int*   labels = (const int*)d_in[1];
    float*       out    = (float*)d_out;
    float*       part   = (float*)d_ws;

    const int B = in_sizes[1];
    const int C = in_sizes[0] / B;        // 1000 for this problem

    if (C == 1000) {
        const int grid = (B + WPB * RPW - 1) / (WPB * RPW);   // 2048
        topk_pipe<250><<<grid, WPB * 64, 0, stream>>>(logits, labels, part, B);
        reduce_partials<<<1, 256, 0, stream>>>(part, out, grid, 1.0f / (float)B);
    } else {
        const int grid = (B + WPB - 1) / WPB;
        topk_generic<<<grid, WPB * 64, 0, stream>>>(logits, labels, part, B, C);
        reduce_partials<<<1, 256, 0, stream>>>(part, out, grid, 1.0f / (float)B);
    }
}

// Round 4
// 185.758 us; speedup vs baseline: 1.0999x; 1.0999x over previous
//
#include <hip/hip_runtime.h>
#include <math.h>

// GradientBoostingLoss: per-row top-4 hardest negatives + logsumexp, mean over rows.
// R4: 32 lanes per row, 2 rows per wave concurrently. 8 independent float4 loads
// per lane (deep MLP, single base addr + imm offsets), 5-stage butterfly whose
// shuffles serve both rows at once, logsumexp tail amortized over 2 rows.
// Partials in d_ws + tiny reducer; no same-address atomics anywhere.

#define WPB 4   // waves per block (256 threads)

__device__ __forceinline__ void ce(float &a, float &b) {
    float hi = fmaxf(a, b), lo = fminf(a, b); a = hi; b = lo;
}

// Sort float4 descending (x >= y >= z >= w): 5 compare-exchanges.
__device__ __forceinline__ void sort4d(float4 &v) {
    ce(v.x, v.y); ce(v.z, v.w); ce(v.x, v.z); ce(v.y, v.w); ce(v.y, v.z);
}

// Merge two sorted-desc top-4 lists -> sorted-desc top-4 of union (12 ops).
__device__ __forceinline__ void merge4(float o0, float o1, float o2, float o3,
                                       float &t0, float &t1, float &t2, float &t3) {
    float c0 = fmaxf(t0, o3);
    float c1 = fmaxf(t1, o2);
    float c2 = fmaxf(t2, o1);
    float c3 = fmaxf(t3, o0);
    float d0 = fmaxf(c0, c2), d2 = fminf(c0, c2);
    float d1 = fmaxf(c1, c3), d3 = fminf(c1, c3);
    t0 = fmaxf(d0, d1); t1 = fminf(d0, d1);
    t2 = fmaxf(d2, d3); t3 = fminf(d2, d3);
}

__device__ __forceinline__ void mergef4(float4 s, float &t0, float &t1, float &t2, float &t3) {
    merge4(s.x, s.y, s.z, s.w, t0, t1, t2, t3);
}

// Capture label logit from quad q (if present) and mask it to -inf. qL/sub wave-varying
// only across half-waves (per row group); sub branch is cheap.
__device__ __forceinline__ void grab(float4 &v, int q, int qL, int sub, float &labv) {
    if (q == qL) {
        labv = (sub == 0) ? v.x : (sub == 1) ? v.y : (sub == 2) ? v.z : v.w;
        if      (sub == 0) v.x = -INFINITY;
        else if (sub == 1) v.y = -INFINITY;
        else if (sub == 2) v.z = -INFINITY;
        else               v.w = -INFINITY;
    }
}

// NQ = quads per row; requires 224 < NQ <= 256 (exactly 8 strided loads per lane).
template<int NQ>
__global__ __launch_bounds__(256, 6) void topk32(
    const float* __restrict__ logits, const int* __restrict__ labels,
    float* __restrict__ partial, int B)
{
    static_assert(NQ > 224 && NQ <= 256, "topk32 requires 224 < NQ <= 256");
    const int wid  = threadIdx.x >> 6;
    const int lane = threadIdx.x & 63;
    const int s    = lane & 31;          // sublane within row group
    const int g    = lane >> 5;          // row group 0/1 within wave

    const int rowraw = (blockIdx.x * WPB + wid) * 2 + g;
    const bool valid = rowraw < B;
    const int row    = valid ? rowraw : B - 1;

    const float4* rp = (const float4*)(logits + (size_t)row * (size_t)(NQ * 4));

    // 8 strided quads per lane: q = s + 32*j. j=7 may exceed NQ -> clamp + mask.
    const bool v7 = (s + 224) < NQ;
    const int  q7 = v7 ? (s + 224) : (NQ - 1);

    // Issue all 8 loads back-to-back (one base, immediate offsets for j=0..6).
    float4 a0 = rp[s];
    float4 a1 = rp[s + 32];
    float4 a2 = rp[s + 64];
    float4 a3 = rp[s + 96];
    float4 a4 = rp[s + 128];
    float4 a5 = rp[s + 160];
    float4 a6 = rp[s + 192];
    float4 a7 = rp[q7];
    const int L  = labels[row];
    const int qL = L >> 2, sub = L & 3;

    float labv = -INFINITY;
    grab(a0, s,       qL, sub, labv);
    grab(a1, s + 32,  qL, sub, labv);
    grab(a2, s + 64,  qL, sub, labv);
    grab(a3, s + 96,  qL, sub, labv);
    grab(a4, s + 128, qL, sub, labv);
    grab(a5, s + 160, qL, sub, labv);
    grab(a6, s + 192, qL, sub, labv);
    grab(a7, q7,      qL, sub, labv);    // clamped lanes may spuriously capture; value identical
    if (!v7) a7 = make_float4(-INFINITY, -INFINITY, -INFINITY, -INFINITY);

    // Label owner sublane within the group is qL & 31 (q = s + 32j => s = qL mod 32).
    const float lab = __shfl(labv, (g << 5) | (qL & 31), 64);

    // Per-lane top-4 of 32 values: 8x sort4 + 7x merge4 tree.
    sort4d(a0); sort4d(a1); sort4d(a2); sort4d(a3);
    sort4d(a4); sort4d(a5); sort4d(a6); sort4d(a7);
    float t0 = a0.x, t1 = a0.y, t2 = a0.z, t3 = a0.w;
    mergef4(a1, t0, t1, t2, t3);
    float u0 = a2.x, u1 = a2.y, u2 = a2.z, u3 = a2.w;
    mergef4(a3, u0, u1, u2, u3);
    float w0 = a4.x, w1 = a4.y, w2 = a4.z, w3 = a4.w;
    mergef4(a5, w0, w1, w2, w3);
    float x0 = a6.x, x1 = a6.y, x2 = a6.z, x3 = a6.w;
    mergef4(a7, x0, x1, x2, x3);
    merge4(u0, u1, u2, u3, t0, t1, t2, t3);
    merge4(x0, x1, x2, x3, w0, w1, w2, w3);
    merge4(w0, w1, w2, w3, t0, t1, t2, t3);

    // 5-stage butterfly within each 32-lane group (xor masks < 32 never cross groups).
    // One shuffle instruction reduces BOTH rows of the wave simultaneously.
    #pragma unroll
    for (int m = 1; m < 32; m <<= 1) {
        float o0 = __shfl_xor(t0, m, 64);
        float o1 = __shfl_xor(t1, m, 64);
        float o2 = __shfl_xor(t2, m, 64);
        float o3 = __shfl_xor(t3, m, 64);
        merge4(o0, o1, o2, o3, t0, t1, t2, t3);
    }

    // loss = logsumexp([lab, t0..t3]) - lab (uniform within each 32-lane group)
    float mx = fmaxf(lab, t0);
    float sm = expf(lab - mx) + expf(t0 - mx) + expf(t1 - mx)
             + expf(t2 - mx) + expf(t3 - mx);
    float loss = valid ? (logf(sm) + mx - lab) : 0.0f;

    // Wave sum: lane 0 holds group-0 loss, lane 32 holds group-1 loss.
    float other = __shfl(loss, 32, 64);   // executed by all lanes
    __shared__ float s_loss[WPB];
    if (lane == 0) s_loss[wid] = loss + other;
    __syncthreads();
    if (threadIdx.x == 0)
        partial[blockIdx.x] = s_loss[0] + s_loss[1] + s_loss[2] + s_loss[3];
}

// Generic fallback (1 row per 64-lane wave) for shapes != C=1000.
__global__ __launch_bounds__(256) void topk_generic(
    const float* __restrict__ logits, const int* __restrict__ labels,
    float* __restrict__ partial, int B, int C)
{
    const int wid  = threadIdx.x >> 6;
    const int lane = threadIdx.x & 63;
    const int row  = blockIdx.x * WPB + wid;

    __shared__ float s_loss[WPB];
    float loss = 0.0f;
    if (row < B) {
        const float4* rp = (const float4*)(logits + (size_t)row * (size_t)C);
        const int nq  = C >> 2;
        const int L   = labels[row];
        const int qL  = L >> 2;
        const int sub = L & 3;

        float t0 = -INFINITY, t1 = -INFINITY, t2 = -INFINITY, t3 = -INFINITY;
        float labv = -INFINITY;
        for (int q = lane; q < nq; q += 64) {
            float4 v = rp[q];
            grab(v, q, qL, sub, labv);
            sort4d(v);
            merge4(v.x, v.y, v.z, v.w, t0, t1, t2, t3);
        }
        for (int c = (nq << 2) + lane; c < C; c += 64) {
            float v = logits[(size_t)row * (size_t)C + c];
            if (c == L) { labv = v; v = -INFINITY; }
            merge4(v, -INFINITY, -INFINITY, -INFINITY, t0, t1, t2, t3);
        }
        float lab = labv;
        #pragma unroll
        for (int m = 1; m < 64; m <<= 1) {
            float o0 = __shfl_xor(t0, m, 64);
            float o1 = __shfl_xor(t1, m, 64);
            float o2 = __shfl_xor(t2, m, 64);
            float o3 = __shfl_xor(t3, m, 64);
            float ol = __shfl_xor(lab, m, 64);
            merge4(o0, o1, o2, o3, t0, t1, t2, t3);
            lab = fmaxf(lab, ol);
        }
        float mx = fmaxf(lab, t0);
        float sm = expf(lab - mx) + expf(t0 - mx) + expf(t1 - mx)
                 + expf(t2 - mx) + expf(t3 - mx);
        loss = logf(sm) + mx - lab;
    }

    if (lane == 0) s_loss[wid] = loss;
    __syncthreads();
    if (threadIdx.x == 0)
        partial[blockIdx.x] = s_loss[0] + s_loss[1] + s_loss[2] + s_loss[3];
}

__global__ __launch_bounds__(256) void reduce_partials(
    const float* __restrict__ partial, float* __restrict__ out, int n, float invB)
{
    __shared__ float s_sum[WPB];
    float s = 0.0f;
    if ((n & 3) == 0) {
        const float4* p4 = (const float4*)partial;
        const int n4 = n >> 2;
        float s0 = 0, s1 = 0, s2 = 0, s3 = 0;   // independent accumulators
        for (int i = threadIdx.x; i < n4; i += 1024) {
            int i0 = i, i1 = i + 256, i2 = i + 512, i3 = i + 768;
            if (i0 < n4) { float4 v = p4[i0]; s0 += (v.x + v.y) + (v.z + v.w); }
            if (i1 < n4) { float4 v = p4[i1]; s1 += (v.x + v.y) + (v.z + v.w); }
            if (i2 < n4) { float4 v = p4[i2]; s2 += (v.x + v.y) + (v.z + v.w); }
            if (i3 < n4) { float4 v = p4[i3]; s3 += (v.x + v.y) + (v.z + v.w); }
        }
        s = (s0 + s1) + (s2 + s3);
    } else {
        for (int i = threadIdx.x; i < n; i += 256) s += partial[i];
    }
    #pragma unroll
    for (int m = 32; m >= 1; m >>= 1) s += __shfl_down(s, m, 64);
    const int wid  = threadIdx.x >> 6;
    const int lane = threadIdx.x & 63;
    if (lane == 0) s_sum[wid] = s;
    __syncthreads();
    if (threadIdx.x == 0)
        *out = (s_sum[0] + s_sum[1] + s_sum[2] + s_sum[3]) * invB;
}

extern "C" void kernel_launch(void* const* d_in, const int* in_sizes, int n_in,
                              void* d_out, int out_size, void* d_ws, size_t ws_size,
                              hipStream_t stream) {
    const float* logits = (const float*)d_in[0];
    const int*   labels = (const int*)d_in[1];
    float*       out    = (float*)d_out;
    float*       part   = (float*)d_ws;

    const int B = in_sizes[1];
    const int C = in_sizes[0] / B;        // 1000 for this problem

    if (C == 1000) {
        const int rows_per_block = 2 * WPB;                    // 8
        const int grid = (B + rows_per_block - 1) / rows_per_block;  // 4096
        topk32<250><<<grid, WPB * 64, 0, stream>>>(logits, labels, part, B);
        reduce_partials<<<1, 256, 0, stream>>>(part, out, grid, 1.0f / (float)B);
    } else {
        const int grid = (B + WPB - 1) / WPB;
        topk_generic<<<grid, WPB * 64, 0, stream>>>(logits, labels, part, B, C);
        reduce_partials<<<1, 256, 0, stream>>>(part, out, grid, 1.0f / (float)B);
    }
}

// Round 5
// 185.280 us; speedup vs baseline: 1.1028x; 1.0026x over previous
//
#include <hip/hip_runtime.h>
#include <math.h>

// GradientBoostingLoss: per-row top-4 hardest negatives + logsumexp, mean over rows.
// R5: 16 lanes per row, 4 rows per wave. 16 float4 loads/lane (one base + imm
// offsets), per-lane top-4 via sort4 + binary merge tree, then a 4-stage ALL-DPP
// butterfly (quad_perm xor1/xor2, row_ror:4, row_ror:8) — ZERO DS-pipe ops.
// Each DPP stage reduces 4 rows simultaneously; label logit rides the same
// stages as a max-reduce. Partials + tiny reducer; no same-address atomics.

#define WPB 4   // waves per block (256 threads)

__device__ __forceinline__ void ce(float &a, float &b) {
    float hi = fmaxf(a, b), lo = fminf(a, b); a = hi; b = lo;
}

// Sort float4 descending (x >= y >= z >= w): 5 compare-exchanges.
__device__ __forceinline__ void sort4d(float4 &v) {
    ce(v.x, v.y); ce(v.z, v.w); ce(v.x, v.z); ce(v.y, v.w); ce(v.y, v.z);
}

// Merge two sorted-desc top-4 lists -> sorted-desc top-4 of union (12 ops).
__device__ __forceinline__ void merge4(float o0, float o1, float o2, float o3,
                                       float &t0, float &t1, float &t2, float &t3) {
    float c0 = fmaxf(t0, o3);
    float c1 = fmaxf(t1, o2);
    float c2 = fmaxf(t2, o1);
    float c3 = fmaxf(t3, o0);
    float d0 = fmaxf(c0, c2), d2 = fminf(c0, c2);
    float d1 = fmaxf(c1, c3), d3 = fminf(c1, c3);
    t0 = fmaxf(d0, d1); t1 = fminf(d0, d1);
    t2 = fmaxf(d2, d3); t3 = fminf(d2, d3);
}

__device__ __forceinline__ void mrg(float4 &d, const float4 s) {
    merge4(s.x, s.y, s.z, s.w, d.x, d.y, d.z, d.w);
}

// Capture label logit from quad q (if present) and mask it to -inf.
__device__ __forceinline__ void grab(float4 &v, int q, int qL, int sub, float &labv) {
    if (q == qL) {
        labv = (sub == 0) ? v.x : (sub == 1) ? v.y : (sub == 2) ? v.z : v.w;
        if      (sub == 0) v.x = -INFINITY;
        else if (sub == 1) v.y = -INFINITY;
        else if (sub == 2) v.z = -INFINITY;
        else               v.w = -INFINITY;
    }
}

// DPP cross-lane move (row-local, VALU-speed). CTRL: 0xB1=xor1 quad_perm,
// 0x4E=xor2 quad_perm, 0x124=row_ror:4, 0x128=row_ror:8.
template<int CTRL>
__device__ __forceinline__ float dppf(float x) {
    int i = __float_as_int(x);
    return __int_as_float(__builtin_amdgcn_update_dpp(i, i, CTRL, 0xF, 0xF, false));
}

// NQ = quads per row; requires 239 < NQ <= 256 (16 strided loads per 16-lane group).
template<int NQ>
__global__ __launch_bounds__(256) void topk16(
    const float* __restrict__ logits, const int* __restrict__ labels,
    float* __restrict__ partial, int B)
{
    static_assert(NQ > 239 && NQ <= 256, "topk16 requires 239 < NQ <= 256");
    const int wid  = threadIdx.x >> 6;
    const int lane = threadIdx.x & 63;
    const int s    = lane & 15;          // sublane within 16-lane row group
    const int g    = lane >> 4;          // row group 0..3 within wave

    const int rowraw = (blockIdx.x * WPB + wid) * 4 + g;
    const bool valid = rowraw < B;
    const int row    = valid ? rowraw : B - 1;

    const float4* rp = (const float4*)(logits + (size_t)row * (size_t)(NQ * 4));

    // 16 strided quads per lane: q = s + 16*j, j=0..15. j<=14 always in range
    // (s+224 <= 239 < NQ); j=15 may exceed -> clamp + mask after grab.
    const bool v15 = (s + 240) < NQ;
    const int  q15 = v15 ? (s + 240) : (NQ - 1);

    float4 a0  = rp[s];
    float4 a1  = rp[s + 16];
    float4 a2  = rp[s + 32];
    float4 a3  = rp[s + 48];
    float4 a4  = rp[s + 64];
    float4 a5  = rp[s + 80];
    float4 a6  = rp[s + 96];
    float4 a7  = rp[s + 112];
    float4 a8  = rp[s + 128];
    float4 a9  = rp[s + 144];
    float4 a10 = rp[s + 160];
    float4 a11 = rp[s + 176];
    float4 a12 = rp[s + 192];
    float4 a13 = rp[s + 208];
    float4 a14 = rp[s + 224];
    float4 a15 = rp[q15];
    const int L  = labels[row];
    const int qL = L >> 2, sub = L & 3;

    float labv = -INFINITY;
    grab(a0,  s,       qL, sub, labv);
    grab(a1,  s + 16,  qL, sub, labv);
    grab(a2,  s + 32,  qL, sub, labv);
    grab(a3,  s + 48,  qL, sub, labv);
    grab(a4,  s + 64,  qL, sub, labv);
    grab(a5,  s + 80,  qL, sub, labv);
    grab(a6,  s + 96,  qL, sub, labv);
    grab(a7,  s + 112, qL, sub, labv);
    grab(a8,  s + 128, qL, sub, labv);
    grab(a9,  s + 144, qL, sub, labv);
    grab(a10, s + 160, qL, sub, labv);
    grab(a11, s + 176, qL, sub, labv);
    grab(a12, s + 192, qL, sub, labv);
    grab(a13, s + 208, qL, sub, labv);
    grab(a14, s + 224, qL, sub, labv);
    grab(a15, q15,     qL, sub, labv);   // clamped lanes capture duplicate value: harmless
    if (!v15) a15 = make_float4(-INFINITY, -INFINITY, -INFINITY, -INFINITY); // kill dup elements

    // Per-lane top-4 of 64 values: 16x sort4 + 15-merge binary tree.
    sort4d(a0);  sort4d(a1);  sort4d(a2);  sort4d(a3);
    sort4d(a4);  sort4d(a5);  sort4d(a6);  sort4d(a7);
    sort4d(a8);  sort4d(a9);  sort4d(a10); sort4d(a11);
    sort4d(a12); sort4d(a13); sort4d(a14); sort4d(a15);
    mrg(a0, a1);   mrg(a2, a3);   mrg(a4, a5);   mrg(a6, a7);
    mrg(a8, a9);   mrg(a10, a11); mrg(a12, a13); mrg(a14, a15);
    mrg(a0, a2);   mrg(a4, a6);   mrg(a8, a10);  mrg(a12, a14);
    mrg(a0, a4);   mrg(a8, a12);
    mrg(a0, a8);
    float t0 = a0.x, t1 = a0.y, t2 = a0.z, t3 = a0.w;

    // 4-stage all-DPP butterfly within each 16-lane row group.
    // Rotate-merge schedule: after xor1+xor2 each lane holds top4 of its aligned
    // 4-lane group; ror:4 merges a disjoint group; ror:8 merges the remaining
    // disjoint half -> every source element counted exactly once (top-k-safe).
    // The label logit max-reduces through the same stages.
    #define BSTAGE(CTRL) do {                                                  \
        float o0 = dppf<CTRL>(t0), o1 = dppf<CTRL>(t1);                        \
        float o2 = dppf<CTRL>(t2), o3 = dppf<CTRL>(t3);                        \
        labv = fmaxf(labv, dppf<CTRL>(labv));                                  \
        merge4(o0, o1, o2, o3, t0, t1, t2, t3);                                \
    } while (0)
    BSTAGE(0xB1);   // quad_perm [1,0,3,2] : xor 1
    BSTAGE(0x4E);   // quad_perm [2,3,0,1] : xor 2
    BSTAGE(0x124);  // row_ror:4
    BSTAGE(0x128);  // row_ror:8
    #undef BSTAGE
    const float lab = labv;              // row max of labv = true-label logit

    // loss = logsumexp([lab, t0..t3]) - lab (uniform across the 16-lane group)
    float mx = fmaxf(lab, t0);
    float sm = expf(lab - mx) + expf(t0 - mx) + expf(t1 - mx)
             + expf(t2 - mx) + expf(t3 - mx);
    float loss = valid ? (logf(sm) + mx - lab) : 0.0f;

    __shared__ float s_loss[WPB * 4];
    if (s == 0) s_loss[(wid << 2) | g] = loss;
    __syncthreads();
    if (threadIdx.x == 0) {
        float acc = 0.0f;
        #pragma unroll
        for (int i = 0; i < WPB * 4; ++i) acc += s_loss[i];
        partial[blockIdx.x] = acc;       // one plain store per block
    }
}

// Generic fallback (1 row per 64-lane wave) for shapes != C=1000.
__global__ __launch_bounds__(256) void topk_generic(
    const float* __restrict__ logits, const int* __restrict__ labels,
    float* __restrict__ partial, int B, int C)
{
    const int wid  = threadIdx.x >> 6;
    const int lane = threadIdx.x & 63;
    const int row  = blockIdx.x * WPB + wid;

    __shared__ float s_loss[WPB];
    float loss = 0.0f;
    if (row < B) {
        const float4* rp = (const float4*)(logits + (size_t)row * (size_t)C);
        const int nq  = C >> 2;
        const int L   = labels[row];
        const int qL  = L >> 2;
        const int sub = L & 3;

        float t0 = -INFINITY, t1 = -INFINITY, t2 = -INFINITY, t3 = -INFINITY;
        float labv = -INFINITY;
        for (int q = lane; q < nq; q += 64) {
            float4 v = rp[q];
            grab(v, q, qL, sub, labv);
            sort4d(v);
            merge4(v.x, v.y, v.z, v.w, t0, t1, t2, t3);
        }
        for (int c = (nq << 2) + lane; c < C; c += 64) {
            float v = logits[(size_t)row * (size_t)C + c];
            if (c == L) { labv = v; v = -INFINITY; }
            merge4(v, -INFINITY, -INFINITY, -INFINITY, t0, t1, t2, t3);
        }
        float lab = labv;
        #pragma unroll
        for (int m = 1; m < 64; m <<= 1) {
            float o0 = __shfl_xor(t0, m, 64);
            float o1 = __shfl_xor(t1, m, 64);
            float o2 = __shfl_xor(t2, m, 64);
            float o3 = __shfl_xor(t3, m, 64);
            float ol = __shfl_xor(lab, m, 64);
            merge4(o0, o1, o2, o3, t0, t1, t2, t3);
            lab = fmaxf(lab, ol);
        }
        float mx = fmaxf(lab, t0);
        float sm = expf(lab - mx) + expf(t0 - mx) + expf(t1 - mx)
                 + expf(t2 - mx) + expf(t3 - mx);
        loss = logf(sm) + mx - lab;
    }

    if (lane == 0) s_loss[wid] = loss;
    __syncthreads();
    if (threadIdx.x == 0)
        partial[blockIdx.x] = s_loss[0] + s_loss[1] + s_loss[2] + s_loss[3];
}

__global__ __launch_bounds__(256) void reduce_partials(
    const float* __restrict__ partial, float* __restrict__ out, int n, float invB)
{
    __shared__ float s_sum[WPB];
    float s = 0.0f;
    if ((n & 3) == 0) {
        const float4* p4 = (const float4*)partial;
        const int n4 = n >> 2;
        float s0 = 0, s1 = 0, s2 = 0, s3 = 0;
        for (int i = threadIdx.x; i < n4; i += 1024) {
            int i0 = i, i1 = i + 256, i2 = i + 512, i3 = i + 768;
            if (i0 < n4) { float4 v = p4[i0]; s0 += (v.x + v.y) + (v.z + v.w); }
            if (i1 < n4) { float4 v = p4[i1]; s1 += (v.x + v.y) + (v.z + v.w); }
            if (i2 < n4) { float4 v = p4[i2]; s2 += (v.x + v.y) + (v.z + v.w); }
            if (i3 < n4) { float4 v = p4[i3]; s3 += (v.x + v.y) + (v.z + v.w); }
        }
        s = (s0 + s1) + (s2 + s3);
    } else {
        for (int i = threadIdx.x; i < n; i += 256) s += partial[i];
    }
    #pragma unroll
    for (int m = 32; m >= 1; m >>= 1) s += __shfl_down(s, m, 64);
    const int wid  = threadIdx.x >> 6;
    const int lane = threadIdx.x & 63;
    if (lane == 0) s_sum[wid] = s;
    __syncthreads();
    if (threadIdx.x == 0)
        *out = (s_sum[0] + s_sum[1] + s_sum[2] + s_sum[3]) * invB;
}

extern "C" void kernel_launch(void* const* d_in, const int* in_sizes, int n_in,
                              void* d_out, int out_size, void* d_ws, size_t ws_size,
                              hipStream_t stream) {
    const float* logits = (const float*)d_in[0];
    const int*   labels = (const int*)d_in[1];
    float*       out    = (float*)d_out;
    float*       part   = (float*)d_ws;

    const int B = in_sizes[1];
    const int C = in_sizes[0] / B;        // 1000 for this problem

    if (C == 1000) {
        const int rows_per_block = 4 * WPB;                          // 16
        const int grid = (B + rows_per_block - 1) / rows_per_block;  // 2048
        topk16<250><<<grid, WPB * 64, 0, stream>>>(logits, labels, part, B);
        reduce_partials<<<1, 256, 0, stream>>>(part, out, grid, 1.0f / (float)B);
    } else {
        const int grid = (B + WPB - 1) / WPB;
        topk_generic<<<grid, WPB * 64, 0, stream>>>(logits, labels, part, B, C);
        reduce_partials<<<1, 256, 0, stream>>>(part, out, grid, 1.0f / (float)B);
    }
}

// Round 6
// 177.849 us; speedup vs baseline: 1.1489x; 1.0418x over previous
//
#include <hip/hip_runtime.h>
#include <math.h>

// GradientBoostingLoss: per-row top-4 hardest negatives + logsumexp, mean over rows.
// R6: 16 lanes/row, 4 rows/wave. Label + label-logit gathered FIRST so data-load
// consumption order == issue order (fine-grained vmcnt, no full drain). Nontemporal
// streaming loads. Mask-only grab (no extract). All-DPP 4-stage butterfly.
// launch_bounds(256,4) for VGPR headroom so all 16 loads stay in flight.

#define WPB 4   // waves per block (256 threads)

typedef float vf4 __attribute__((ext_vector_type(4)));

__device__ __forceinline__ float4 ntload(const float* p) {
    vf4 v = __builtin_nontemporal_load((const vf4*)p);
    return make_float4(v.x, v.y, v.z, v.w);
}

__device__ __forceinline__ void ce(float &a, float &b) {
    float hi = fmaxf(a, b), lo = fminf(a, b); a = hi; b = lo;
}

// Sort float4 descending: 5 compare-exchanges.
__device__ __forceinline__ void sort4d(float4 &v) {
    ce(v.x, v.y); ce(v.z, v.w); ce(v.x, v.z); ce(v.y, v.w); ce(v.y, v.z);
}

// Merge two sorted-desc top-4 lists -> sorted-desc top-4 of union (12 ops).
__device__ __forceinline__ void merge4(float o0, float o1, float o2, float o3,
                                       float &t0, float &t1, float &t2, float &t3) {
    float c0 = fmaxf(t0, o3);
    float c1 = fmaxf(t1, o2);
    float c2 = fmaxf(t2, o1);
    float c3 = fmaxf(t3, o0);
    float d0 = fmaxf(c0, c2), d2 = fminf(c0, c2);
    float d1 = fmaxf(c1, c3), d3 = fminf(c1, c3);
    t0 = fmaxf(d0, d1); t1 = fminf(d0, d1);
    t2 = fmaxf(d2, d3); t3 = fminf(d2, d3);
}

__device__ __forceinline__ void mrgv(float4 &d, const float4 s) {
    merge4(s.x, s.y, s.z, s.w, d.x, d.y, d.z, d.w);
}

// Mask the label element to -inf if it lives in quad q (value already gathered).
__device__ __forceinline__ void maskq(float4 &v, int q, int qL, int sub) {
    if (q == qL) {
        if      (sub == 0) v.x = -INFINITY;
        else if (sub == 1) v.y = -INFINITY;
        else if (sub == 2) v.z = -INFINITY;
        else               v.w = -INFINITY;
    }
}

// DPP cross-lane (row-local, VALU-speed). 0xB1=xor1, 0x4E=xor2, 0x124=row_ror:4, 0x128=row_ror:8.
template<int CTRL>
__device__ __forceinline__ float dppf(float x) {
    int i = __float_as_int(x);
    return __int_as_float(__builtin_amdgcn_update_dpp(i, i, CTRL, 0xF, 0xF, false));
}

// NQ = quads per row; requires 239 < NQ <= 256.
template<int NQ>
__global__ __launch_bounds__(256, 4) void topk16(
    const float* __restrict__ logits, const int* __restrict__ labels,
    float* __restrict__ partial, int B)
{
    static_assert(NQ > 239 && NQ <= 256, "topk16 requires 239 < NQ <= 256");
    const int wid  = threadIdx.x >> 6;
    const int lane = threadIdx.x & 63;
    const int s    = lane & 15;          // sublane within 16-lane row group
    const int g    = lane >> 4;          // row group 0..3

    const int rowraw = (blockIdx.x * WPB + wid) * 4 + g;
    const bool valid = rowraw < B;
    const int row    = valid ? rowraw : B - 1;
    const float* rowp = logits + (size_t)row * (size_t)(NQ * 4);

    // ---- label chain FIRST: these two loads are issued before any data load,
    // so consuming a0 later only needs the oldest vmcnt slots (no full drain).
    const int L  = labels[row];
    const int qL = L >> 2, sub = L & 3;
    const float lab = rowp[L];           // 16 lanes/group hit the same address (broadcast)

    // ---- 16 streaming data loads, issue order == consumption order.
    const bool v15 = (s + 240) < NQ;
    const int  q15 = v15 ? (s + 240) : (NQ - 1);
    float4 a0  = ntload(rowp + 4 * (s));
    float4 a1  = ntload(rowp + 4 * (s + 16));
    float4 a2  = ntload(rowp + 4 * (s + 32));
    float4 a3  = ntload(rowp + 4 * (s + 48));
    float4 a4  = ntload(rowp + 4 * (s + 64));
    float4 a5  = ntload(rowp + 4 * (s + 80));
    float4 a6  = ntload(rowp + 4 * (s + 96));
    float4 a7  = ntload(rowp + 4 * (s + 112));
    float4 a8  = ntload(rowp + 4 * (s + 128));
    float4 a9  = ntload(rowp + 4 * (s + 144));
    float4 a10 = ntload(rowp + 4 * (s + 160));
    float4 a11 = ntload(rowp + 4 * (s + 176));
    float4 a12 = ntload(rowp + 4 * (s + 192));
    float4 a13 = ntload(rowp + 4 * (s + 208));
    float4 a14 = ntload(rowp + 4 * (s + 224));
    float4 a15 = ntload(rowp + 4 * q15);

    // ---- consume in arrival order; two parallel merge chains for ILP while
    // later loads are still in flight.
    maskq(a0, s,      qL, sub); sort4d(a0);
    maskq(a1, s + 16, qL, sub); sort4d(a1);
    float4 t = a0; mrgv(t, a1);                   // chain A
    maskq(a2, s + 32, qL, sub); sort4d(a2);
    maskq(a3, s + 48, qL, sub); sort4d(a3);
    float4 u = a2; mrgv(u, a3);                   // chain B
    maskq(a4, s + 64, qL, sub); sort4d(a4); mrgv(t, a4);
    maskq(a5, s + 80, qL, sub); sort4d(a5); mrgv(u, a5);
    maskq(a6, s + 96, qL, sub); sort4d(a6); mrgv(t, a6);
    maskq(a7, s + 112, qL, sub); sort4d(a7); mrgv(u, a7);
    maskq(a8, s + 128, qL, sub); sort4d(a8); mrgv(t, a8);
    maskq(a9, s + 144, qL, sub); sort4d(a9); mrgv(u, a9);
    maskq(a10, s + 160, qL, sub); sort4d(a10); mrgv(t, a10);
    maskq(a11, s + 176, qL, sub); sort4d(a11); mrgv(u, a11);
    maskq(a12, s + 192, qL, sub); sort4d(a12); mrgv(t, a12);
    maskq(a13, s + 208, qL, sub); sort4d(a13); mrgv(u, a13);
    maskq(a14, s + 224, qL, sub); sort4d(a14); mrgv(t, a14);
    maskq(a15, q15,     qL, sub);
    if (!v15) a15 = make_float4(-INFINITY, -INFINITY, -INFINITY, -INFINITY);
    sort4d(a15); mrgv(u, a15);
    mrgv(t, u);
    float t0 = t.x, t1 = t.y, t2 = t.z, t3 = t.w;

    // ---- 4-stage all-DPP butterfly within each 16-lane row group.
    // xor1, xor2 (quad-local), then ror:4 and ror:8 merge disjoint groups:
    // every source element counted exactly once (top-k-safe).
    #define BSTAGE(CTRL) do {                                                  \
        float o0 = dppf<CTRL>(t0), o1 = dppf<CTRL>(t1);                        \
        float o2 = dppf<CTRL>(t2), o3 = dppf<CTRL>(t3);                        \
        merge4(o0, o1, o2, o3, t0, t1, t2, t3);                                \
    } while (0)
    BSTAGE(0xB1);   // quad_perm [1,0,3,2] : xor 1
    BSTAGE(0x4E);   // quad_perm [2,3,0,1] : xor 2
    BSTAGE(0x124);  // row_ror:4
    BSTAGE(0x128);  // row_ror:8
    #undef BSTAGE

    // loss = logsumexp([lab, t0..t3]) - lab (uniform across the 16-lane group)
    float mx = fmaxf(lab, t0);
    float sm = expf(lab - mx) + expf(t0 - mx) + expf(t1 - mx)
             + expf(t2 - mx) + expf(t3 - mx);
    float loss = valid ? (logf(sm) + mx - lab) : 0.0f;

    __shared__ float s_loss[WPB * 4];
    if (s == 0) s_loss[(wid << 2) | g] = loss;
    __syncthreads();
    if (threadIdx.x == 0) {
        float acc = 0.0f;
        #pragma unroll
        for (int i = 0; i < WPB * 4; ++i) acc += s_loss[i];
        partial[blockIdx.x] = acc;
    }
}

// Generic fallback (1 row per 64-lane wave) for shapes != C=1000.
__device__ __forceinline__ void grab(float4 &v, int q, int qL, int sub, float &labv) {
    if (q == qL) {
        labv = (sub == 0) ? v.x : (sub == 1) ? v.y : (sub == 2) ? v.z : v.w;
        if      (sub == 0) v.x = -INFINITY;
        else if (sub == 1) v.y = -INFINITY;
        else if (sub == 2) v.z = -INFINITY;
        else               v.w = -INFINITY;
    }
}

__global__ __launch_bounds__(256) void topk_generic(
    const float* __restrict__ logits, const int* __restrict__ labels,
    float* __restrict__ partial, int B, int C)
{
    const int wid  = threadIdx.x >> 6;
    const int lane = threadIdx.x & 63;
    const int row  = blockIdx.x * WPB + wid;

    __shared__ float s_loss[WPB];
    float loss = 0.0f;
    if (row < B) {
        const float4* rp = (const float4*)(logits + (size_t)row * (size_t)C);
        const int nq  = C >> 2;
        const int L   = labels[row];
        const int qL  = L >> 2;
        const int sub = L & 3;

        float t0 = -INFINITY, t1 = -INFINITY, t2 = -INFINITY, t3 = -INFINITY;
        float labv = -INFINITY;
        for (int q = lane; q < nq; q += 64) {
            float4 v = rp[q];
            grab(v, q, qL, sub, labv);
            sort4d(v);
            merge4(v.x, v.y, v.z, v.w, t0, t1, t2, t3);
        }
        for (int c = (nq << 2) + lane; c < C; c += 64) {
            float v = logits[(size_t)row * (size_t)C + c];
            if (c == L) { labv = v; v = -INFINITY; }
            merge4(v, -INFINITY, -INFINITY, -INFINITY, t0, t1, t2, t3);
        }
        float lab = labv;
        #pragma unroll
        for (int m = 1; m < 64; m <<= 1) {
            float o0 = __shfl_xor(t0, m, 64);
            float o1 = __shfl_xor(t1, m, 64);
            float o2 = __shfl_xor(t2, m, 64);
            float o3 = __shfl_xor(t3, m, 64);
            float ol = __shfl_xor(lab, m, 64);
            merge4(o0, o1, o2, o3, t0, t1, t2, t3);
            lab = fmaxf(lab, ol);
        }
        float mx = fmaxf(lab, t0);
        float sm = expf(lab - mx) + expf(t0 - mx) + expf(t1 - mx)
                 + expf(t2 - mx) + expf(t3 - mx);
        loss = logf(sm) + mx - lab;
    }

    if (lane == 0) s_loss[wid] = loss;
    __syncthreads();
    if (threadIdx.x == 0)
        partial[blockIdx.x] = s_loss[0] + s_loss[1] + s_loss[2] + s_loss[3];
}

__global__ __launch_bounds__(256) void reduce_partials(
    const float* __restrict__ partial, float* __restrict__ out, int n, float invB)
{
    __shared__ float s_sum[WPB];
    float s = 0.0f;
    if ((n & 3) == 0) {
        const float4* p4 = (const float4*)partial;
        const int n4 = n >> 2;
        float s0 = 0, s1 = 0, s2 = 0, s3 = 0;
        for (int i = threadIdx.x; i < n4; i += 1024) {
            int i0 = i, i1 = i + 256, i2 = i + 512, i3 = i + 768;
            if (i0 < n4) { float4 v = p4[i0]; s0 += (v.x + v.y) + (v.z + v.w); }
            if (i1 < n4) { float4 v = p4[i1]; s1 += (v.x + v.y) + (v.z + v.w); }
            if (i2 < n4) { float4 v = p4[i2]; s2 += (v.x + v.y) + (v.z + v.w); }
            if (i3 < n4) { float4 v = p4[i3]; s3 += (v.x + v.y) + (v.z + v.w); }
        }
        s = (s0 + s1) + (s2 + s3);
    } else {
        for (int i = threadIdx.x; i < n; i += 256) s += partial[i];
    }
    #pragma unroll
    for (int m = 32; m >= 1; m >>= 1) s += __shfl_down(s, m, 64);
    const int wid  = threadIdx.x >> 6;
    const int lane = threadIdx.x & 63;
    if (lane == 0) s_sum[wid] = s;
    __syncthreads();
    if (threadIdx.x == 0)
        *out = (s_sum[0] + s_sum[1] + s_sum[2] + s_sum[3]) * invB;
}

extern "C" void kernel_launch(void* const* d_in, const int* in_sizes, int n_in,
                              void* d_out, int out_size, void* d_ws, size_t ws_size,
                              hipStream_t stream) {
    const float* logits = (const float*)d_in[0];
    const int*   labels = (const int*)d_in[1];
    float*       out    = (float*)d_out;
    float*       part   = (float*)d_ws;

    const int B = in_sizes[1];
    const int C = in_sizes[0] / B;        // 1000 for this problem

    if (C == 1000) {
        const int rows_per_block = 4 * WPB;                          // 16
        const int grid = (B + rows_per_block - 1) / rows_per_block;  // 2048
        topk16<250><<<grid, WPB * 64, 0, stream>>>(logits, labels, part, B);
        reduce_partials<<<1, 256, 0, stream>>>(part, out, grid, 1.0f / (float)B);
    } else {
        const int grid = (B + WPB - 1) / WPB;
        topk_generic<<<grid, WPB * 64, 0, stream>>>(logits, labels, part, B, C);
        reduce_partials<<<1, 256, 0, stream>>>(part, out, grid, 1.0f / (float)B);
    }
}